// Round 10
// baseline (49.559 us; speedup 1.0000x reference)
//
#include <hip/hip_runtime.h>

// Constrained sparsemax: p = clip(z - tau, 0, u), tau s.t. sum p = 1.
// R9 core: one wave per row, DPP reductions, NT stores, f64 polish on the
// GLOBAL bracket (regions must match numpy's f64 tau).
// New in R10: phase 1 evaluates TWO probes per iteration (midpoint +
// endpoint false-position) with their 4 partial sums reduced through four
// per-level-interleaved DPP chains (latency of ~one chain). Midpoint
// guarantees halving; false-position lands exactly once the bracket lies
// in a single linear segment -> ~halves the serial iteration count.

typedef float vfloat4 __attribute__((ext_vector_type(4)));

template<int CTRL>
__device__ __forceinline__ float dpp_zero(float v) {   // invalid lanes -> 0
  return __builtin_bit_cast(float,
    __builtin_amdgcn_update_dpp(0, __builtin_bit_cast(int, v), CTRL, 0xf, 0xf, true));
}
template<int CTRL>
__device__ __forceinline__ float dpp_ident(float v, float ident) { // invalid -> ident
  return __builtin_bit_cast(float,
    __builtin_amdgcn_update_dpp(__builtin_bit_cast(int, ident),
                                __builtin_bit_cast(int, v), CTRL, 0xf, 0xf, false));
}
__device__ __forceinline__ float rl63(float v) {
  return __builtin_bit_cast(float,
    __builtin_amdgcn_readlane(__builtin_bit_cast(int, v), 63));
}

__device__ __forceinline__ float wave_sum(float v) {
  v += dpp_zero<0x111>(v); v += dpp_zero<0x112>(v); v += dpp_zero<0x114>(v);
  v += dpp_zero<0x118>(v); v += dpp_zero<0x142>(v); v += dpp_zero<0x143>(v);
  return rl63(v);
}
// Four interleaved full-wave sums (each result uniform across the wave).
__device__ __forceinline__ void wave_sum4(float& a, float& b, float& c, float& d) {
#define SUM4_STEP(CT) \
  a += dpp_zero<CT>(a); b += dpp_zero<CT>(b); c += dpp_zero<CT>(c); d += dpp_zero<CT>(d);
  SUM4_STEP(0x111) SUM4_STEP(0x112) SUM4_STEP(0x114)
  SUM4_STEP(0x118) SUM4_STEP(0x142) SUM4_STEP(0x143)
#undef SUM4_STEP
  a = rl63(a); b = rl63(b); c = rl63(c); d = rl63(d);
}
// init: two maxes + one sum, chains interleaved per level
__device__ __forceinline__ void wave_mms(float& a, float& b, float& s) {
  const float NI = -3.4028235e38f;
#define MMS_STEP(CT) \
  a = fmaxf(a, dpp_ident<CT>(a, NI)); b = fmaxf(b, dpp_ident<CT>(b, NI)); \
  s += dpp_zero<CT>(s);
  MMS_STEP(0x111) MMS_STEP(0x112) MMS_STEP(0x114)
  MMS_STEP(0x118) MMS_STEP(0x142) MMS_STEP(0x143)
#undef MMS_STEP
  a = rl63(a); b = rl63(b); s = rl63(s);
}
// phase 2: one f64 sum + one f32 sum, interleaved
__device__ __forceinline__ void wave_sumd_f(double& A, float& c) {
#define SUMD_STEP(CT) { \
  unsigned long long xa = __builtin_bit_cast(unsigned long long, A); \
  int al = __builtin_amdgcn_update_dpp(0, (int)(unsigned)xa, CT, 0xf, 0xf, true); \
  int ah = __builtin_amdgcn_update_dpp(0, (int)(xa >> 32),   CT, 0xf, 0xf, true); \
  c += dpp_zero<CT>(c); \
  A += __builtin_bit_cast(double, ((unsigned long long)(unsigned)ah << 32) | (unsigned)al); }
  SUMD_STEP(0x111) SUMD_STEP(0x112) SUMD_STEP(0x114)
  SUMD_STEP(0x118) SUMD_STEP(0x142) SUMD_STEP(0x143)
#undef SUMD_STEP
  { unsigned long long x = __builtin_bit_cast(unsigned long long, A);
    int l = __builtin_amdgcn_readlane((int)(unsigned)x, 63);
    int h = __builtin_amdgcn_readlane((int)(x >> 32), 63);
    A = __builtin_bit_cast(double, ((unsigned long long)(unsigned)h << 32) | (unsigned)l); }
  c = rl63(c);
}

__global__ __launch_bounds__(256)
void csparsemax_kernel(const float* __restrict__ z, const float* __restrict__ u,
                       float* __restrict__ out, int B) {
  constexpr int K = 1024;
  const int lane = threadIdx.x & 63;
  const int wv = threadIdx.x >> 6;
  const int row = blockIdx.x * 4 + wv;
  if (row >= B) return;
  const size_t base = (size_t)row * (size_t)K;

  // --- load 16 elems/lane as 4x float4, coalesced ---
  float zf[16], uf[16];
  const vfloat4* z4p = (const vfloat4*)(z + base);
  const vfloat4* u4p = (const vfloat4*)(u + base);
  #pragma unroll
  for (int j = 0; j < 4; ++j) {
    vfloat4 a = z4p[j * 64 + lane];
    vfloat4 b = u4p[j * 64 + lane];
    zf[j*4+0] = a.x; zf[j*4+1] = a.y; zf[j*4+2] = a.z; zf[j*4+3] = a.w;
    uf[j*4+0] = b.x; uf[j*4+1] = b.y; uf[j*4+2] = b.z; uf[j*4+3] = b.w;
  }

  // --- bracket [lo,hi] + sum(u): g(lo)=sum u-1 > 0 > -1 = g(hi) ---
  float a = -3.4028235e38f, m = -3.4028235e38f, su = 0.f;
  #pragma unroll
  for (int t = 0; t < 16; ++t) {
    a = fmaxf(a, uf[t] - zf[t]);    // lo = -max(u-z) = min(z-u)
    m = fmaxf(m, zf[t]);
    su += uf[t];
  }
  wave_mms(a, m, su);
  float lo = -a, hi = m;
  const double glo = (double)lo, ghi = (double)hi;

  // --- phase 1: dual-probe (midpoint + false-position) on
  //     g(tau) = sum med3(z-tau,0,u) - 1, monotone non-increasing ---
  float gl = su - 1.f;               // g(lo) > 0
  float gh = -1.f;                   // g(hi) < 0
  for (int it = 0; it < 16; ++it) {
    float tm = 0.5f * (lo + hi);
    if (tm == lo || tm == hi) break;             // f32 resolution reached
    float tf = (lo * gh - hi * gl) / (gh - gl);  // false-position point
    if (!(tf > lo && tf < hi)) tf = tm;
    float p1 = fminf(tm, tf), p2 = fmaxf(tm, tf);
    float A1 = 0.f, B1 = 0.f, A2 = 0.f, B2 = 0.f;
    #pragma unroll
    for (int t = 0; t < 16; t += 2) {            // v_med3_f32 per elem/probe
      A1 += fminf(fmaxf(zf[t]   - p1, 0.f), uf[t]);
      B1 += fminf(fmaxf(zf[t+1] - p1, 0.f), uf[t+1]);
      A2 += fminf(fmaxf(zf[t]   - p2, 0.f), uf[t]);
      B2 += fminf(fmaxf(zf[t+1] - p2, 0.f), uf[t+1]);
    }
    wave_sum4(A1, B1, A2, B2);
    float g1 = (A1 + B1) - 1.f;
    float g2 = (A2 + B2) - 1.f;
    if (g1 < 0.f)       { hi = p1; gh = g1; }    // root < p1
    else if (g1 == 0.f) { lo = hi = p1; break; } // exact (f32) root
    else if (g2 > 0.f)  { lo = p2; gl = g2; }    // root > p2
    else if (g2 == 0.f) { lo = hi = p2; break; }
    else                { lo = p1; gl = g1; hi = p2; gh = g2; } // sign change inside
  }
  float tau;
  if (lo == hi) {
    tau = lo;
  } else {
    tau = (lo * gh - hi * gl) / (gh - gl);       // best interpolant
    if (!(tau >= lo && tau <= hi)) tau = 0.5f * (lo + hi);
  }

  // --- phase 2: f64 segment-Newton polish, GLOBAL bracket (exactness) ---
  double dlo = glo, dhi = ghi, taud = (double)tau;
  for (int it = 0; it < 24; ++it) {
    double Sd = 0.0;
    float Cf = 0.f;                              // count exact in f32
    #pragma unroll
    for (int t = 0; t < 16; ++t) {
      double x = (double)zf[t] - taud;
      double ud = (double)uf[t];
      if (x >= ud)      { Sd += ud; }
      else if (x > 0.0) { Sd += (double)zf[t]; Cf += 1.f; }
    }
    wave_sumd_f(Sd, Cf);
    double C = (double)Cf;
    double f = Sd - C * taud;
    if (f == 1.0 && C > 0.5) break;
    if (f > 1.0) dlo = taud; else dhi = taud;
    double next;
    if (C > 0.5) {
      double cand = (Sd - 1.0) / C;              // exact segment root
      if (cand == taud) break;
      next = (cand > dlo && cand < dhi) ? cand : 0.5 * (dlo + dhi);
    } else {
      next = 0.5 * (dlo + dhi);
    }
    if (next == taud) break;
    taud = next;
  }

  // --- epilogue: p/val in f32, regions via f64 compares, NT stores ---
  float* out_p = out;
  float* out_r = out + (size_t)B * (size_t)K;
  float* out_t = out + 2ull * (size_t)B * (size_t)K;
  float* out_v = out_t + B;

  const float tf = (float)taud;
  float vloc = 0.f;
  #pragma unroll
  for (int j = 0; j < 4; ++j) {
    vfloat4 p4, r4;
    #pragma unroll
    for (int q = 0; q < 4; ++q) {
      int t = j * 4 + q;
      float pf = fminf(fmaxf(zf[t] - tf, 0.f), uf[t]);   // v_med3_f32
      float d = pf - zf[t];
      vloc = fmaf(d, d, vloc);
      double xd = (double)zf[t] - taud;                  // numpy-exact bounds
      float rg = (xd <= 0.0) ? 0.f : ((xd >= (double)uf[t]) ? 2.f : 1.f);
      p4[q] = pf;
      r4[q] = rg;
    }
    __builtin_nontemporal_store(p4, &((vfloat4*)(out_p + base))[j * 64 + lane]);
    __builtin_nontemporal_store(r4, &((vfloat4*)(out_r + base))[j * 64 + lane]);
  }

  float vtot = wave_sum(vloc);
  if (lane == 0) {
    out_t[row] = tf;
    out_v[row] = 0.5f * vtot;
  }
}

extern "C" void kernel_launch(void* const* d_in, const int* in_sizes, int n_in,
                              void* d_out, int out_size, void* d_ws, size_t ws_size,
                              hipStream_t stream) {
  const float* z = (const float*)d_in[0];
  const float* u = (const float*)d_in[1];
  float* out = (float*)d_out;
  const int K = 1024;
  const int B = in_sizes[0] / K;
  const int blocks = (B + 3) / 4;
  csparsemax_kernel<<<blocks, 256, 0, stream>>>(z, u, out, B);
}

// Round 11
// 37.556 us; speedup vs baseline: 1.3196x; 1.3196x over previous
//
#include <hip/hip_runtime.h>

// Constrained sparsemax: p = clip(z - tau, 0, u), tau s.t. sum p = 1.
// R9 algorithm verbatim (best measured: secant phase-1 on f via med3, one
// DPP chain per iteration; f64 segment-Newton polish on the GLOBAL bracket;
// f32 epilogue with f64 region compares; NT stores).
// R11 change: ONE-WAVE BLOCKS (64 threads, 8192 blocks). Single-wave
// workgroups schedule independently -> straggler rows don't hold 3 sibling
// waves' resources, and more waves pack per SIMD to hide the serial
// iteration-chain latency.

typedef float vfloat4 __attribute__((ext_vector_type(4)));

template<int CTRL>
__device__ __forceinline__ float dpp_zero(float v) {   // invalid lanes -> 0
  return __builtin_bit_cast(float,
    __builtin_amdgcn_update_dpp(0, __builtin_bit_cast(int, v), CTRL, 0xf, 0xf, true));
}
template<int CTRL>
__device__ __forceinline__ float dpp_ident(float v, float ident) { // invalid -> ident
  return __builtin_bit_cast(float,
    __builtin_amdgcn_update_dpp(__builtin_bit_cast(int, ident),
                                __builtin_bit_cast(int, v), CTRL, 0xf, 0xf, false));
}
__device__ __forceinline__ float rl63(float v) {
  return __builtin_bit_cast(float,
    __builtin_amdgcn_readlane(__builtin_bit_cast(int, v), 63));
}

__device__ __forceinline__ float wave_sum(float v) {
  v += dpp_zero<0x111>(v); v += dpp_zero<0x112>(v); v += dpp_zero<0x114>(v);
  v += dpp_zero<0x118>(v); v += dpp_zero<0x142>(v); v += dpp_zero<0x143>(v);
  return rl63(v);
}
// init: two maxes + one sum, chains interleaved per level
__device__ __forceinline__ void wave_mms(float& a, float& b, float& s) {
  const float NI = -3.4028235e38f;
#define MMS_STEP(CT) \
  a = fmaxf(a, dpp_ident<CT>(a, NI)); b = fmaxf(b, dpp_ident<CT>(b, NI)); \
  s += dpp_zero<CT>(s);
  MMS_STEP(0x111) MMS_STEP(0x112) MMS_STEP(0x114)
  MMS_STEP(0x118) MMS_STEP(0x142) MMS_STEP(0x143)
#undef MMS_STEP
  a = rl63(a); b = rl63(b); s = rl63(s);
}
// phase 2: one f64 sum + one f32 sum, interleaved
__device__ __forceinline__ void wave_sumd_f(double& A, float& c) {
#define SUMD_STEP(CT) { \
  unsigned long long xa = __builtin_bit_cast(unsigned long long, A); \
  int al = __builtin_amdgcn_update_dpp(0, (int)(unsigned)xa, CT, 0xf, 0xf, true); \
  int ah = __builtin_amdgcn_update_dpp(0, (int)(xa >> 32),   CT, 0xf, 0xf, true); \
  c += dpp_zero<CT>(c); \
  A += __builtin_bit_cast(double, ((unsigned long long)(unsigned)ah << 32) | (unsigned)al); }
  SUMD_STEP(0x111) SUMD_STEP(0x112) SUMD_STEP(0x114)
  SUMD_STEP(0x118) SUMD_STEP(0x142) SUMD_STEP(0x143)
#undef SUMD_STEP
  { unsigned long long x = __builtin_bit_cast(unsigned long long, A);
    int l = __builtin_amdgcn_readlane((int)(unsigned)x, 63);
    int h = __builtin_amdgcn_readlane((int)(x >> 32), 63);
    A = __builtin_bit_cast(double, ((unsigned long long)(unsigned)h << 32) | (unsigned)l); }
  c = rl63(c);
}

__global__ __launch_bounds__(64)
void csparsemax_kernel(const float* __restrict__ z, const float* __restrict__ u,
                       float* __restrict__ out, int B) {
  constexpr int K = 1024;
  const int lane = threadIdx.x & 63;
  const int row = blockIdx.x;
  if (row >= B) return;
  const size_t base = (size_t)row * (size_t)K;

  // --- load 16 elems/lane as 4x float4, coalesced ---
  float zf[16], uf[16];
  const vfloat4* z4p = (const vfloat4*)(z + base);
  const vfloat4* u4p = (const vfloat4*)(u + base);
  #pragma unroll
  for (int j = 0; j < 4; ++j) {
    vfloat4 a = z4p[j * 64 + lane];
    vfloat4 b = u4p[j * 64 + lane];
    zf[j*4+0] = a.x; zf[j*4+1] = a.y; zf[j*4+2] = a.z; zf[j*4+3] = a.w;
    uf[j*4+0] = b.x; uf[j*4+1] = b.y; uf[j*4+2] = b.z; uf[j*4+3] = b.w;
  }

  // --- bracket [lo,hi] + sum(u): f(lo)=sum u >= 1 > 0 = f(hi) ---
  float a = -3.4028235e38f, m = -3.4028235e38f, su = 0.f;
  #pragma unroll
  for (int t = 0; t < 16; ++t) {
    a = fmaxf(a, uf[t] - zf[t]);    // lo = -max(u-z) = min(z-u)
    m = fmaxf(m, zf[t]);
    su += uf[t];
  }
  wave_mms(a, m, su);
  float lo = -a, hi = m;
  const double glo = (double)lo, ghi = (double)hi;

  // --- phase 1: secant on g(tau) = sum med3(z-tau,0,u) - 1 ---
  float t_prev = hi, g_prev = -1.f;              // g(hi) = -1
  float tau = (lo + hi * (su - 1.f)) / su;       // secant((lo,su-1),(hi,-1))
  if (!(tau > lo && tau < hi)) tau = 0.5f * (lo + hi);
  for (int it = 0; it < 48; ++it) {
    float f0 = 0.f, f1 = 0.f, f2 = 0.f, f3 = 0.f;
    #pragma unroll
    for (int t = 0; t < 16; t += 4) {            // v_med3_f32 per elem
      f0 += fminf(fmaxf(zf[t+0] - tau, 0.f), uf[t+0]);
      f1 += fminf(fmaxf(zf[t+1] - tau, 0.f), uf[t+1]);
      f2 += fminf(fmaxf(zf[t+2] - tau, 0.f), uf[t+2]);
      f3 += fminf(fmaxf(zf[t+3] - tau, 0.f), uf[t+3]);
    }
    float g = wave_sum((f0 + f1) + (f2 + f3)) - 1.f;
    if (g == 0.f) break;
    if (g > 0.f) lo = tau; else hi = tau;
    // secant root through (t_prev, g_prev), (tau, g); NaN/inf/out-of-bracket
    // all fail the range check -> midpoint fallback
    float cand = (tau * g_prev - t_prev * g) / (g_prev - g);
    t_prev = tau; g_prev = g;
    float next = (cand > lo && cand < hi) ? cand : 0.5f * (lo + hi);
    if (next == tau) break;                      // f32 resolution reached
    tau = next;
  }

  // --- phase 2: f64 segment-Newton polish, GLOBAL bracket (exactness) ---
  double dlo = glo, dhi = ghi, taud = (double)tau;
  for (int it = 0; it < 24; ++it) {
    double Sd = 0.0;
    float Cf = 0.f;                              // count exact in f32
    #pragma unroll
    for (int t = 0; t < 16; ++t) {
      double x = (double)zf[t] - taud;
      double ud = (double)uf[t];
      if (x >= ud)      { Sd += ud; }
      else if (x > 0.0) { Sd += (double)zf[t]; Cf += 1.f; }
    }
    wave_sumd_f(Sd, Cf);
    double C = (double)Cf;
    double f = Sd - C * taud;
    if (f == 1.0 && C > 0.5) break;
    if (f > 1.0) dlo = taud; else dhi = taud;
    double next;
    if (C > 0.5) {
      double cand = (Sd - 1.0) / C;              // exact segment root
      if (cand == taud) break;
      next = (cand > dlo && cand < dhi) ? cand : 0.5 * (dlo + dhi);
    } else {
      next = 0.5 * (dlo + dhi);
    }
    if (next == taud) break;
    taud = next;
  }

  // --- epilogue: p/val in f32, regions via f64 compares, NT stores ---
  float* out_p = out;
  float* out_r = out + (size_t)B * (size_t)K;
  float* out_t = out + 2ull * (size_t)B * (size_t)K;
  float* out_v = out_t + B;

  const float tf = (float)taud;
  float vloc = 0.f;
  #pragma unroll
  for (int j = 0; j < 4; ++j) {
    vfloat4 p4, r4;
    #pragma unroll
    for (int q = 0; q < 4; ++q) {
      int t = j * 4 + q;
      float pf = fminf(fmaxf(zf[t] - tf, 0.f), uf[t]);   // v_med3_f32
      float d = pf - zf[t];
      vloc = fmaf(d, d, vloc);
      double xd = (double)zf[t] - taud;                  // numpy-exact bounds
      float rg = (xd <= 0.0) ? 0.f : ((xd >= (double)uf[t]) ? 2.f : 1.f);
      p4[q] = pf;
      r4[q] = rg;
    }
    __builtin_nontemporal_store(p4, &((vfloat4*)(out_p + base))[j * 64 + lane]);
    __builtin_nontemporal_store(r4, &((vfloat4*)(out_r + base))[j * 64 + lane]);
  }

  float vtot = wave_sum(vloc);
  if (lane == 0) {
    out_t[row] = tf;
    out_v[row] = 0.5f * vtot;
  }
}

extern "C" void kernel_launch(void* const* d_in, const int* in_sizes, int n_in,
                              void* d_out, int out_size, void* d_ws, size_t ws_size,
                              hipStream_t stream) {
  const float* z = (const float*)d_in[0];
  const float* u = (const float*)d_in[1];
  float* out = (float*)d_out;
  const int K = 1024;
  const int B = in_sizes[0] / K;
  csparsemax_kernel<<<B, 64, 0, stream>>>(z, u, out, B);
}